// Round 6
// baseline (165.978 us; speedup 1.0000x reference)
//
#include <hip/hip_runtime.h>

// Problem constants (B=4, S=2048, H=1024, E=8)
#define H 1024
#define E 8
#define T 8192          // B*S
#define CAP 1024        // T/E, capacity_factor=1.0 top-1

typedef __bf16 bf16x8 __attribute__((ext_vector_type(8)));
typedef float  f32x4  __attribute__((ext_vector_type(4)));
typedef unsigned short u16;

// round-to-nearest-even f32 -> bf16 bits
__device__ __forceinline__ u16 f2bf(float f) {
    union { float f; unsigned u; } v; v.f = f;
    unsigned r = v.u + 0x7FFFu + ((v.u >> 16) & 1u);
    return (u16)(r >> 16);
}

// packed f32x2 -> bf16x2 (RNE), gfx950 hw instruction (no builtin)
__device__ __forceinline__ unsigned cvt2bf(float lo, float hi) {
    unsigned r;
    asm("v_cvt_pk_bf16_f32 %0, %1, %2" : "=v"(r) : "v"(lo), "v"(hi));
    return r;
}

// async global->LDS, 16 B per lane
typedef __attribute__((address_space(1))) const void* gas_t;
typedef __attribute__((address_space(3))) void* las_t;
__device__ __forceinline__ void gld16(const void* g, void* l) {
    __builtin_amdgcn_global_load_lds((gas_t)g, (las_t)l, 16, 0, 0);
}

// ---------------------------------------------------------------------------
// Kernel 1: gating + x->bf16 only (512 blocks, 16 tok/block). No W pass:
// the GEMM eats fp32 W directly via reg-staged cvt. Gate math identical to
// all prior passing versions.
// ---------------------------------------------------------------------------
__global__ __launch_bounds__(256) void gate_kernel(
    const float* __restrict__ x, const float* __restrict__ wg,
    int* __restrict__ eid, float* __restrict__ gate, u16* __restrict__ xbf) {
    const int tid = threadIdx.x;
    const int wv = tid >> 6, lane = tid & 63;
    const int tbase = blockIdx.x * 16 + wv * 4;
    const int h00 = lane * 4;

    float a[4][8];
    #pragma unroll
    for (int j = 0; j < 4; ++j)
        #pragma unroll
        for (int e = 0; e < 8; ++e) a[j][e] = 0.f;

    #pragma unroll
    for (int q = 0; q < 4; ++q) {
        const int h0 = q * 256 + h00;
        float4 xv[4];
        #pragma unroll
        for (int j = 0; j < 4; ++j)
            xv[j] = *(const float4*)(x + (size_t)(tbase + j) * H + h0);
        #pragma unroll
        for (int j = 0; j < 4; ++j) {
            ushort4 o;
            o.x = f2bf(xv[j].x); o.y = f2bf(xv[j].y);
            o.z = f2bf(xv[j].z); o.w = f2bf(xv[j].w);
            *(ushort4*)(xbf + (size_t)(tbase + j) * H + h0) = o;
        }
        float wr[4][8];
        #pragma unroll
        for (int r = 0; r < 4; ++r) {
            const float4* p = (const float4*)(wg + (size_t)(h0 + r) * E);
            float4 lo = p[0], hi = p[1];
            wr[r][0] = lo.x; wr[r][1] = lo.y; wr[r][2] = lo.z; wr[r][3] = lo.w;
            wr[r][4] = hi.x; wr[r][5] = hi.y; wr[r][6] = hi.z; wr[r][7] = hi.w;
        }
        #pragma unroll
        for (int e = 0; e < 8; ++e)
            #pragma unroll
            for (int j = 0; j < 4; ++j)
                a[j][e] += xv[j].x * wr[0][e] + xv[j].y * wr[1][e]
                         + xv[j].z * wr[2][e] + xv[j].w * wr[3][e];
    }

    const bool b0 = lane & 1, b1 = lane & 2, b2 = lane & 4;
    const int elane = ((lane & 1) << 2) | (lane & 2) | ((lane >> 2) & 1);

    #pragma unroll
    for (int j = 0; j < 4; ++j) {
        float* A = a[j];
        #pragma unroll
        for (int k = 0; k < 4; ++k) {
            float t = b0 ? A[k] : A[k + 4];
            t = __shfl_xor(t, 1);
            A[k] = (b0 ? A[k + 4] : A[k]) + t;
        }
        #pragma unroll
        for (int k = 0; k < 2; ++k) {
            float t = b1 ? A[k] : A[k + 2];
            t = __shfl_xor(t, 2);
            A[k] = (b1 ? A[k + 2] : A[k]) + t;
        }
        {
            float t = b2 ? A[0] : A[1];
            t = __shfl_xor(t, 4);
            A[0] = (b2 ? A[1] : A[0]) + t;
        }
        float v = A[0];
        v += __shfl_xor(v, 8); v += __shfl_xor(v, 16); v += __shfl_xor(v, 32);
        float m = v; int mi = elane;
        #pragma unroll
        for (int off = 1; off <= 4; off <<= 1) {
            float om = __shfl_xor(m, off);
            int   oi = __shfl_xor(mi, off);
            if (om > m || (om == m && oi < mi)) { m = om; mi = oi; }
        }
        float s = expf(v - m);
        s += __shfl_xor(s, 1); s += __shfl_xor(s, 2); s += __shfl_xor(s, 4);
        if (lane == 0) {
            eid[tbase + j]  = mi;
            gate[tbase + j] = 1.0f / s;
        }
    }
}

// ---------------------------------------------------------------------------
// Kernel 2: capacity scan, 1024 threads, serial depth 8.
// ---------------------------------------------------------------------------
#define SCAN_T 1024
#define STPT 8
__global__ __launch_bounds__(1024) void scan_kernel(
    const int* __restrict__ eid, float* __restrict__ gate,
    int* __restrict__ perm) {
    __shared__ int cnt[SCAN_T][E];     // 32 KB
    __shared__ int part[E][32];
    const int tid = threadIdx.x;

    for (int i = tid; i < E * CAP; i += SCAN_T) perm[i] = -1;

    const int t0 = tid * STPT;
    int ei[STPT];
    #pragma unroll
    for (int i = 0; i < STPT; ++i) ei[i] = eid[t0 + i];

    int c[E];
    #pragma unroll
    for (int e = 0; e < E; ++e) c[e] = 0;
    #pragma unroll
    for (int i = 0; i < STPT; ++i)
        #pragma unroll
        for (int e = 0; e < E; ++e) c[e] += (ei[i] == e);
    #pragma unroll
    for (int e = 0; e < E; ++e) cnt[tid][e] = c[e];
    __syncthreads();

    if (tid < 256) {                       // 8 experts x 32 groups of 32
        const int e = tid >> 5, g = tid & 31;
        int s = 0;
        for (int i = g * 32; i < g * 32 + 32; ++i) s += cnt[i][e];
        part[e][g] = s;
    }
    __syncthreads();
    if (tid < E) {
        int run = 0;
        #pragma unroll
        for (int g = 0; g < 32; ++g) { int v = part[tid][g]; part[tid][g] = run; run += v; }
    }
    __syncthreads();
    if (tid < 256) {                       // scatter exclusive bases back into cnt
        const int e = tid >> 5, g = tid & 31;
        int run = part[e][g];
        for (int i = g * 32; i < g * 32 + 32; ++i) { int v = cnt[i][e]; cnt[i][e] = run; run += v; }
    }
    __syncthreads();

    #pragma unroll
    for (int e = 0; e < E; ++e) c[e] = cnt[tid][e];
    #pragma unroll
    for (int i = 0; i < STPT; ++i) {
        const int t = t0 + i, e0 = ei[i];
        int pos = 0;
        #pragma unroll
        for (int k = 0; k < E; ++k) if (e0 == k) pos = c[k]++;
        if (pos < CAP) perm[e0 * CAP + pos] = t;
        else gate[t] = 0.f;               // dropped; kept tokens have gate >= 1/8
    }
}

// ---------------------------------------------------------------------------
// Kernel 3: gathered GEMM, 128x128 tile, BK=64, depth-2 ring, 2 blocks/CU.
// A: bf16 xbf via global_load_lds (linear dest, pre-swizzled global chunk).
// B: fp32 W reg-staged -> v_cvt_pk_bf16_f32 -> swizzled ds_write_b128, with
// the T14 split: loads ISSUED at the top of compute(t) (sched-fenced so they
// can't sink), cvt+ds_write AFTER the MFMA cluster (the B-reg waitcnt lands
// post-MFMA). One vmcnt(0)+lgkmcnt(0)+s_barrier per K-step.
// WAR: buffer p^1 was last read at step t-1, sealed by that step's barrier.
// Blocks [0,64): zero-dropped-rows plane (LDS-free).
// ---------------------------------------------------------------------------
__global__ __launch_bounds__(512, 4) void moe_gemm_bf(
    const u16* __restrict__ xbf, const float* __restrict__ W,
    const float* __restrict__ bias, const int* __restrict__ perm,
    const float* __restrict__ gate, float* __restrict__ out) {
    __shared__ __align__(16) u16 As[2][128 * 64];   // 2 x 16 KB
    __shared__ __align__(16) u16 Bs[2][128 * 64];   // 2 x 16 KB
    __shared__ int   perm_s[128];
    __shared__ float gate_s[128];

    const int tid = threadIdx.x;
    const int bid = blockIdx.x;

    if (bid < 64) {                 // ---- zero rows of dropped tokens ----
        const int t = bid * 128 + (tid >> 2);
        if (gate[t] == 0.f) {
            const int part = tid & 3;
            float4 z = make_float4(0.f, 0.f, 0.f, 0.f);
            float4* o = (float4*)(out + (size_t)t * H + part * 256);
            #pragma unroll
            for (int i = 0; i < 64; ++i) o[i] = z;
        }
        return;
    }

    const int idx = bid - 64;
    const int e  = idx & 7;           // expert -> XCD (W_e + its tokens on one L2)
    const int mb = (idx >> 3) & 7;    // slot block (128 slots)
    const int fb = idx >> 6;          // feature block (128 features)

    if (tid < 128) {
        const int t = perm[e * CAP + mb * 128 + tid];
        perm_s[tid] = t;
        gate_s[tid] = (t >= 0) ? gate[t] : 0.f;
    }
    __syncthreads();

    const int lane = tid & 63;
    const int wv = tid >> 6;          // 0..7
    const int wm = wv >> 2;           // 0..1 : 64-row half
    const int wn = wv & 3;            // 0..3 : 32-col quarter
    const int l16 = lane & 15, quad = lane >> 4;

    // staging: wave wv covers rows [wv*16, wv*16+16), 8 rows per q-step.
    // LDS[row][c] = G[row][c ^ (row&7)] (chunk = 8 bf16 = 16 B). A achieves
    // this by pre-swizzling the global chunk; B loads chunk gch (2 float4),
    // converts, and writes at lane-linear chunk cch.
    const int rl  = lane >> 3;        // row within 8-row group
    const int cch = lane & 7;
    const int gch = cch ^ rl;
    const u16*   ga[2];
    const float* gb[2];
    #pragma unroll
    for (int q = 0; q < 2; ++q) {
        const int r = wv * 16 + q * 8 + rl;
        const int tA = perm_s[r];
        const int tok = tA >= 0 ? tA : 0;
        ga[q] = xbf + (size_t)tok * H + gch * 8;
        gb[q] = W + (size_t)e * H * H + (size_t)(fb * 128 + r) * H + gch * 8;
    }

    f32x4 acc[4][2] = {};
    float4 nb[2][2];                  // in-flight B tile (16 VGPR)

#define ISSUE(BUF)                                                           \
    {                                                                        \
        _Pragma("unroll")                                                    \
        for (int q = 0; q < 2; ++q) {                                        \
            const float4* p4 = (const float4*)gb[q];                         \
            nb[q][0] = p4[0]; nb[q][1] = p4[1];                              \
        }                                                                    \
        _Pragma("unroll")                                                    \
        for (int q = 0; q < 2; ++q)                                          \
            gld16(ga[q], &As[BUF][(wv * 16 + q * 8) * 64 + lane * 8]);       \
        _Pragma("unroll")                                                    \
        for (int q = 0; q < 2; ++q) { ga[q] += 64; gb[q] += 64; }            \
    }

#define WRITEB(BUF)                                                          \
    {                                                                        \
        _Pragma("unroll")                                                    \
        for (int q = 0; q < 2; ++q) {                                        \
            uint4 v;                                                         \
            v.x = cvt2bf(nb[q][0].x, nb[q][0].y);                            \
            v.y = cvt2bf(nb[q][0].z, nb[q][0].w);                            \
            v.z = cvt2bf(nb[q][1].x, nb[q][1].y);                            \
            v.w = cvt2bf(nb[q][1].z, nb[q][1].w);                            \
            *(uint4*)&Bs[BUF][(wv * 16 + q * 8 + rl) * 64 + cch * 8] = v;    \
        }                                                                    \
    }

    // prologue: stage tile 0 into buffer 0
    ISSUE(0)
    WRITEB(0)
    asm volatile("s_waitcnt vmcnt(0) lgkmcnt(0)" ::: "memory");
    __builtin_amdgcn_sched_barrier(0);
    __builtin_amdgcn_s_barrier();
    __builtin_amdgcn_sched_barrier(0);

    int p = 0;
    #pragma unroll 1
    for (int t = 0; t < 16; ++t) {
        if (t < 15) ISSUE(p ^ 1)            // loads in flight under the MFMAs
        __builtin_amdgcn_sched_barrier(0);  // pin: issue stays above compute

        const u16* cA = As[p];
        const u16* cB = Bs[p];
        __builtin_amdgcn_s_setprio(1);
        #pragma unroll
        for (int kh = 0; kh < 2; ++kh) {
            bf16x8 af[4], bfr[2];
            const int cc = (kh * 4 + quad) ^ (l16 & 7);
            #pragma unroll
            for (int i = 0; i < 4; ++i)
                af[i] = *(const bf16x8*)&cA[(wm * 64 + i * 16 + l16) * 64 + cc * 8];
            #pragma unroll
            for (int i = 0; i < 2; ++i)
                bfr[i] = *(const bf16x8*)&cB[(wn * 32 + i * 16 + l16) * 64 + cc * 8];
            #pragma unroll
            for (int mi = 0; mi < 4; ++mi)
                #pragma unroll
                for (int ni = 0; ni < 2; ++ni)
                    acc[mi][ni] = __builtin_amdgcn_mfma_f32_16x16x32_bf16(
                        af[mi], bfr[ni], acc[mi][ni], 0, 0, 0);
        }
        __builtin_amdgcn_s_setprio(0);
        if (t == 15) break;

        __builtin_amdgcn_sched_barrier(0);  // pin: cvt/write stays below MFMAs
        WRITEB(p ^ 1)                       // compiler waits B-regs here
        __builtin_amdgcn_sched_barrier(0);
        asm volatile("s_waitcnt vmcnt(0) lgkmcnt(0)" ::: "memory");
        __builtin_amdgcn_sched_barrier(0);
        __builtin_amdgcn_s_barrier();       // single barrier per K-step
        __builtin_amdgcn_sched_barrier(0);
        p ^= 1;
    }
#undef ISSUE
#undef WRITEB

    // epilogue: C/D layout col=lane&15, row=quad*4+reg
    float bv[2];
    #pragma unroll
    for (int ni = 0; ni < 2; ++ni)
        bv[ni] = bias[e * H + fb * 128 + wn * 32 + ni * 16 + l16];

    #pragma unroll
    for (int mi = 0; mi < 4; ++mi) {
        #pragma unroll
        for (int r = 0; r < 4; ++r) {
            const int rowl = wm * 64 + mi * 16 + quad * 4 + r;
            const int t = perm_s[rowl];
            if (t < 0) continue;
            const float g = gate_s[rowl];
            float* orow = out + (size_t)t * H + fb * 128 + wn * 32;
            #pragma unroll
            for (int ni = 0; ni < 2; ++ni)
                orow[ni * 16 + l16] = g * (acc[mi][ni][r] + bv[ni]);
        }
    }
}

extern "C" void kernel_launch(void* const* d_in, const int* in_sizes, int n_in,
                              void* d_out, int out_size, void* d_ws, size_t ws_size,
                              hipStream_t stream) {
    const float* x    = (const float*)d_in[0];  // [T,H]
    const float* wg   = (const float*)d_in[1];  // [H,E]
    const float* W    = (const float*)d_in[2];  // [E,H,H]
    const float* bias = (const float*)d_in[3];  // [E,H]
    float* out = (float*)d_out;

    // ws: eid[T] | gate[T] | perm[E*CAP] | xbf[T*H] bf16
    int*   eid  = (int*)d_ws;
    float* gate = (float*)((char*)d_ws + (size_t)T * 4);
    int*   perm = (int*)((char*)d_ws + (size_t)T * 8);
    u16*   xbf  = (u16*)((char*)d_ws + (size_t)T * 12);

    gate_kernel<<<T / 16, 256, 0, stream>>>(x, wg, eid, gate, xbf);
    scan_kernel<<<1, SCAN_T, 0, stream>>>(eid, gate, perm);
    moe_gemm_bf<<<64 + 512, 512, 0, stream>>>(xbf, W, bias, perm, gate, out);
}

// Round 7
// 160.663 us; speedup vs baseline: 1.0331x; 1.0331x over previous
//
#include <hip/hip_runtime.h>

// Problem constants (B=4, S=2048, H=1024, E=8)
#define H 1024
#define E 8
#define T 8192          // B*S
#define CAP 1024        // T/E, capacity_factor=1.0 top-1

typedef __bf16 bf16x8 __attribute__((ext_vector_type(8)));
typedef float  f32x4  __attribute__((ext_vector_type(4)));
typedef unsigned short u16;

// round-to-nearest-even f32 -> bf16 bits
__device__ __forceinline__ u16 f2bf(float f) {
    union { float f; unsigned u; } v; v.f = f;
    unsigned r = v.u + 0x7FFFu + ((v.u >> 16) & 1u);
    return (u16)(r >> 16);
}

// async global->LDS, 16 B per lane
typedef __attribute__((address_space(1))) const void* gas_t;
typedef __attribute__((address_space(3))) void* las_t;
__device__ __forceinline__ void gld16(const void* g, void* l) {
    __builtin_amdgcn_global_load_lds((gas_t)g, (las_t)l, 16, 0, 0);
}

// ---------------------------------------------------------------------------
// Kernel 1: fused gate + x->bf16 (blocks [0,512)) and W->bf16 (blocks
// [512,2048), grid-stride). Proven in r3/r4/r5 benches.
// ---------------------------------------------------------------------------
#define GATE_BLOCKS 512
#define CVT_BLOCKS  1536

__global__ __launch_bounds__(256) void gatecvt_kernel(
    const float* __restrict__ x, const float* __restrict__ wg,
    const float* __restrict__ W,
    int* __restrict__ eid, float* __restrict__ gate,
    u16* __restrict__ xbf, u16* __restrict__ Wbf) {
    const int tid = threadIdx.x;

    if (blockIdx.x >= GATE_BLOCKS) {       // ---- W fp32 -> bf16 ----
        int i = (blockIdx.x - GATE_BLOCKS) * 256 + tid;
        const int n4 = E * H * H / 4;
        const int stride = CVT_BLOCKS * 256;
        for (; i < n4; i += stride) {
            float4 v = ((const float4*)W)[i];
            ushort4 o;
            o.x = f2bf(v.x); o.y = f2bf(v.y); o.z = f2bf(v.z); o.w = f2bf(v.w);
            ((ushort4*)Wbf)[i] = o;
        }
        return;
    }

    // ---- gating, 16 tokens/block (4/wave) ----
    const int wv = tid >> 6, lane = tid & 63;
    const int tbase = blockIdx.x * 16 + wv * 4;
    const int h00 = lane * 4;

    float a[4][8];
    #pragma unroll
    for (int j = 0; j < 4; ++j)
        #pragma unroll
        for (int e = 0; e < 8; ++e) a[j][e] = 0.f;

    #pragma unroll
    for (int q = 0; q < 4; ++q) {
        const int h0 = q * 256 + h00;
        float4 xv[4];
        #pragma unroll
        for (int j = 0; j < 4; ++j)
            xv[j] = *(const float4*)(x + (size_t)(tbase + j) * H + h0);
        #pragma unroll
        for (int j = 0; j < 4; ++j) {
            ushort4 o;
            o.x = f2bf(xv[j].x); o.y = f2bf(xv[j].y);
            o.z = f2bf(xv[j].z); o.w = f2bf(xv[j].w);
            *(ushort4*)(xbf + (size_t)(tbase + j) * H + h0) = o;
        }
        float wr[4][8];
        #pragma unroll
        for (int r = 0; r < 4; ++r) {
            const float4* p = (const float4*)(wg + (size_t)(h0 + r) * E);
            float4 lo = p[0], hi = p[1];
            wr[r][0] = lo.x; wr[r][1] = lo.y; wr[r][2] = lo.z; wr[r][3] = lo.w;
            wr[r][4] = hi.x; wr[r][5] = hi.y; wr[r][6] = hi.z; wr[r][7] = hi.w;
        }
        #pragma unroll
        for (int e = 0; e < 8; ++e)
            #pragma unroll
            for (int j = 0; j < 4; ++j)
                a[j][e] += xv[j].x * wr[0][e] + xv[j].y * wr[1][e]
                         + xv[j].z * wr[2][e] + xv[j].w * wr[3][e];
    }

    const bool b0 = lane & 1, b1 = lane & 2, b2 = lane & 4;
    const int elane = ((lane & 1) << 2) | (lane & 2) | ((lane >> 2) & 1);

    #pragma unroll
    for (int j = 0; j < 4; ++j) {
        float* A = a[j];
        #pragma unroll
        for (int k = 0; k < 4; ++k) {
            float t = b0 ? A[k] : A[k + 4];
            t = __shfl_xor(t, 1);
            A[k] = (b0 ? A[k + 4] : A[k]) + t;
        }
        #pragma unroll
        for (int k = 0; k < 2; ++k) {
            float t = b1 ? A[k] : A[k + 2];
            t = __shfl_xor(t, 2);
            A[k] = (b1 ? A[k + 2] : A[k]) + t;
        }
        {
            float t = b2 ? A[0] : A[1];
            t = __shfl_xor(t, 4);
            A[0] = (b2 ? A[1] : A[0]) + t;
        }
        float v = A[0];
        v += __shfl_xor(v, 8); v += __shfl_xor(v, 16); v += __shfl_xor(v, 32);
        float m = v; int mi = elane;
        #pragma unroll
        for (int off = 1; off <= 4; off <<= 1) {
            float om = __shfl_xor(m, off);
            int   oi = __shfl_xor(mi, off);
            if (om > m || (om == m && oi < mi)) { m = om; mi = oi; }
        }
        float s = expf(v - m);
        s += __shfl_xor(s, 1); s += __shfl_xor(s, 2); s += __shfl_xor(s, 4);
        if (lane == 0) {
            eid[tbase + j]  = mi;
            gate[tbase + j] = 1.0f / s;
        }
    }
}

// ---------------------------------------------------------------------------
// Kernel 2: capacity scan, 1024 threads, serial depth 8. Proven r2-r6.
// ---------------------------------------------------------------------------
#define SCAN_T 1024
#define STPT 8
__global__ __launch_bounds__(1024) void scan_kernel(
    const int* __restrict__ eid, float* __restrict__ gate,
    int* __restrict__ perm) {
    __shared__ int cnt[SCAN_T][E];     // 32 KB
    __shared__ int part[E][32];
    const int tid = threadIdx.x;

    for (int i = tid; i < E * CAP; i += SCAN_T) perm[i] = -1;

    const int t0 = tid * STPT;
    int ei[STPT];
    #pragma unroll
    for (int i = 0; i < STPT; ++i) ei[i] = eid[t0 + i];

    int c[E];
    #pragma unroll
    for (int e = 0; e < E; ++e) c[e] = 0;
    #pragma unroll
    for (int i = 0; i < STPT; ++i)
        #pragma unroll
        for (int e = 0; e < E; ++e) c[e] += (ei[i] == e);
    #pragma unroll
    for (int e = 0; e < E; ++e) cnt[tid][e] = c[e];
    __syncthreads();

    if (tid < 256) {                       // 8 experts x 32 groups of 32
        const int e = tid >> 5, g = tid & 31;
        int s = 0;
        for (int i = g * 32; i < g * 32 + 32; ++i) s += cnt[i][e];
        part[e][g] = s;
    }
    __syncthreads();
    if (tid < E) {
        int run = 0;
        #pragma unroll
        for (int g = 0; g < 32; ++g) { int v = part[tid][g]; part[tid][g] = run; run += v; }
    }
    __syncthreads();
    if (tid < 256) {                       // scatter exclusive bases back into cnt
        const int e = tid >> 5, g = tid & 31;
        int run = part[e][g];
        for (int i = g * 32; i < g * 32 + 32; ++i) { int v = cnt[i][e]; cnt[i][e] = run; run += v; }
    }
    __syncthreads();

    #pragma unroll
    for (int e = 0; e < E; ++e) c[e] = cnt[tid][e];
    #pragma unroll
    for (int i = 0; i < STPT; ++i) {
        const int t = t0 + i, e0 = ei[i];
        int pos = 0;
        #pragma unroll
        for (int k = 0; k < E; ++k) if (e0 == k) pos = c[k]++;
        if (pos < CAP) perm[e0 * CAP + pos] = t;
        else gate[t] = 0.f;               // dropped; kept tokens have gate >= 1/8
    }
}

// ---------------------------------------------------------------------------
// Kernel 3: gathered GEMM, restructured. 128x128 tile, BK=32, 256 threads =
// 4 waves of 64x64 output each: A/B LDS duplication both x2 and per-step
// per-wave 16 MFMA : 8 ds_read_b128 (was 16:12). LDS = 3-deep ring of
// (8KB A + 8KB B) = 50 KB -> 3 blocks/CU (12 waves/CU). Pipeline: at top of
// step t ISSUE tile t+2 into buf[(p+2)%3] (freed at end of t-1); end of step
// one counted s_waitcnt vmcnt(4) (tile t+1 complete, t+2 in flight with ~2
// compute phases to hide) + one s_barrier. Tail: vmcnt(0) at t=30.
// Swizzle (4 chunks of 16B per 64B row): LDS[row][c] = G[row][c ^ (row&3)];
// fragment reads at cc = quad ^ (l16&3) hit 8 even bank-slots (no excess
// conflict). Blocks [0,64): zero-dropped-rows plane (LDS-free).
// ---------------------------------------------------------------------------
__global__ __launch_bounds__(256, 3) void moe_gemm_bf(
    const u16* __restrict__ xbf, const u16* __restrict__ Wbf,
    const float* __restrict__ bias, const int* __restrict__ perm,
    const float* __restrict__ gate, float* __restrict__ out) {
    __shared__ __align__(16) u16 As[3][128 * 32];   // 3 x 8 KB
    __shared__ __align__(16) u16 Bs[3][128 * 32];   // 3 x 8 KB
    __shared__ int   perm_s[128];
    __shared__ float gate_s[128];

    const int tid = threadIdx.x;
    const int bid = blockIdx.x;

    if (bid < 64) {                 // ---- zero rows of dropped tokens ----
        const int t = bid * 128 + (tid >> 1);
        if (gate[t] == 0.f) {
            const int part = tid & 1;
            float4 z = make_float4(0.f, 0.f, 0.f, 0.f);
            float4* o = (float4*)(out + (size_t)t * H + part * 512);
            #pragma unroll
            for (int i = 0; i < 128; ++i) o[i] = z;
        }
        return;
    }

    const int idx = bid - 64;
    const int e  = idx & 7;           // expert -> XCD (W_e + its tokens on one L2)
    const int mb = (idx >> 3) & 7;    // slot block (128 slots)
    const int fb = idx >> 6;          // feature block (128 features)

    if (tid < 128) {
        const int t = perm[e * CAP + mb * 128 + tid];
        perm_s[tid] = t;
        gate_s[tid] = (t >= 0) ? gate[t] : 0.f;
    }
    __syncthreads();

    const int lane = tid & 63;
    const int wv = tid >> 6;          // 0..3
    const int wm = wv >> 1;           // 0..1 : 64-row half
    const int wn = wv & 1;            // 0..1 : 64-col half
    const int l16 = lane & 15, quad = lane >> 4;

    // staging: round q covers rows [q*64, q*64+64), thread -> (row, chunk):
    // row = q*64 + (tid>>2), chunk cch = tid&3; global chunk pre-swizzled
    // gch = cch ^ (row&3). LDS u16 offset = q*2048 + tid*8 (linear in tid,
    // as global_load_lds requires).
    const int srow = tid >> 2;        // 0..63 within round
    const int cch  = tid & 3;
    const int gch  = cch ^ (srow & 3);

    const u16* ga[2];
    const u16* gb[2];
    #pragma unroll
    for (int q = 0; q < 2; ++q) {
        const int r = q * 64 + srow;
        const int tA = perm_s[r];
        const int tok = tA >= 0 ? tA : 0;
        ga[q] = xbf + (size_t)tok * H + gch * 8;
        gb[q] = Wbf + (size_t)e * H * H + (size_t)(fb * 128 + r) * H + gch * 8;
    }

#define ISSUE(BUF)                                                           \
    {                                                                        \
        _Pragma("unroll")                                                    \
        for (int q = 0; q < 2; ++q) {                                        \
            gld16(ga[q], &As[BUF][q * 2048 + tid * 8]);                      \
            gld16(gb[q], &Bs[BUF][q * 2048 + tid * 8]);                      \
        }                                                                    \
        _Pragma("unroll")                                                    \
        for (int q = 0; q < 2; ++q) { ga[q] += 32; gb[q] += 32; }            \
    }

    f32x4 acc[4][4] = {};

    // prologue: stage tiles 0,1 into bufs 0,1; wait tile 0 (tile 1 in flight)
    ISSUE(0)
    ISSUE(1)
    asm volatile("s_waitcnt vmcnt(4)" ::: "memory");
    __builtin_amdgcn_sched_barrier(0);
    __builtin_amdgcn_s_barrier();
    __builtin_amdgcn_sched_barrier(0);

    int p = 0;
    #pragma unroll 1
    for (int t = 0; t < 32; ++t) {
        int nx = p + 2; if (nx >= 3) nx -= 3;
        if (t < 30) ISSUE(nx)               // tile t+2, hidden under 2 phases
        __builtin_amdgcn_sched_barrier(0);

        const u16* cA = As[p];
        const u16* cB = Bs[p];
        const int cc = quad ^ (l16 & 3);
        bf16x8 af[4], bf[4];
        __builtin_amdgcn_s_setprio(1);
        #pragma unroll
        for (int i = 0; i < 4; ++i)
            af[i] = *(const bf16x8*)&cA[(wm * 64 + i * 16 + l16) * 32 + cc * 8];
        #pragma unroll
        for (int i = 0; i < 4; ++i)
            bf[i] = *(const bf16x8*)&cB[(wn * 64 + i * 16 + l16) * 32 + cc * 8];
        #pragma unroll
        for (int mi = 0; mi < 4; ++mi)
            #pragma unroll
            for (int ni = 0; ni < 4; ++ni)
                acc[mi][ni] = __builtin_amdgcn_mfma_f32_16x16x32_bf16(
                    af[mi], bf[ni], acc[mi][ni], 0, 0, 0);
        __builtin_amdgcn_s_setprio(0);
        if (t == 31) break;

        __builtin_amdgcn_sched_barrier(0);
        if (t < 30) asm volatile("s_waitcnt vmcnt(4)" ::: "memory");
        else        asm volatile("s_waitcnt vmcnt(0)" ::: "memory");
        __builtin_amdgcn_sched_barrier(0);
        __builtin_amdgcn_s_barrier();       // single barrier per K-step
        __builtin_amdgcn_sched_barrier(0);
        p = (p == 2) ? 0 : p + 1;
    }
#undef ISSUE

    // epilogue: C/D layout col=lane&15, row=quad*4+reg
    float bv[4];
    #pragma unroll
    for (int ni = 0; ni < 4; ++ni)
        bv[ni] = bias[e * H + fb * 128 + wn * 64 + ni * 16 + l16];

    #pragma unroll
    for (int mi = 0; mi < 4; ++mi) {
        #pragma unroll
        for (int r = 0; r < 4; ++r) {
            const int rowl = wm * 64 + mi * 16 + quad * 4 + r;
            const int t = perm_s[rowl];
            if (t < 0) continue;
            const float g = gate_s[rowl];
            float* orow = out + (size_t)t * H + fb * 128 + wn * 64;
            #pragma unroll
            for (int ni = 0; ni < 4; ++ni)
                orow[ni * 16 + l16] = g * (acc[mi][ni][r] + bv[ni]);
        }
    }
}

extern "C" void kernel_launch(void* const* d_in, const int* in_sizes, int n_in,
                              void* d_out, int out_size, void* d_ws, size_t ws_size,
                              hipStream_t stream) {
    const float* x    = (const float*)d_in[0];  // [T,H]
    const float* wg   = (const float*)d_in[1];  // [H,E]
    const float* W    = (const float*)d_in[2];  // [E,H,H]
    const float* bias = (const float*)d_in[3];  // [E,H]
    float* out = (float*)d_out;

    // ws: eid[T] | gate[T] | perm[E*CAP] | xbf[T*H] bf16 | Wbf[E*H*H] bf16
    int*   eid  = (int*)d_ws;
    float* gate = (float*)((char*)d_ws + (size_t)T * 4);
    int*   perm = (int*)((char*)d_ws + (size_t)T * 8);
    u16*   xbf  = (u16*)((char*)d_ws + (size_t)T * 12);
    u16*   Wbf  = xbf + (size_t)T * H;

    gatecvt_kernel<<<GATE_BLOCKS + CVT_BLOCKS, 256, 0, stream>>>(
        x, wg, W, eid, gate, xbf, Wbf);
    scan_kernel<<<1, SCAN_T, 0, stream>>>(eid, gate, perm);
    moe_gemm_bf<<<64 + 512, 256, 0, stream>>>(xbf, Wbf, bias, perm, gate, out);
}

// Round 8
// 156.848 us; speedup vs baseline: 1.0582x; 1.0243x over previous
//
#include <hip/hip_runtime.h>

// Problem constants (B=4, S=2048, H=1024, E=8)
#define H 1024
#define E 8
#define T 8192          // B*S
#define CAP 1024        // T/E, capacity_factor=1.0 top-1

typedef __bf16 bf16x8 __attribute__((ext_vector_type(8)));
typedef float  f32x4  __attribute__((ext_vector_type(4)));
typedef unsigned short u16;

// round-to-nearest-even f32 -> bf16 bits
__device__ __forceinline__ u16 f2bf(float f) {
    union { float f; unsigned u; } v; v.f = f;
    unsigned r = v.u + 0x7FFFu + ((v.u >> 16) & 1u);
    return (u16)(r >> 16);
}

// async global->LDS, 16 B per lane
typedef __attribute__((address_space(1))) const void* gas_t;
typedef __attribute__((address_space(3))) void* las_t;
__device__ __forceinline__ void gld16(const void* g, void* l) {
    __builtin_amdgcn_global_load_lds((gas_t)g, (las_t)l, 16, 0, 0);
}

// ---------------------------------------------------------------------------
// Kernel 1: fused gate + x->bf16 (blocks [0,512)) and W->bf16 (blocks
// [512,2048), grid-stride). Champion structure; the only change vs the
// 152.5us baseline is reading wg rows directly (register transpose) instead
// of a precomputed wgT -- deletes the separate wgt_kernel launch. Load count
// identical (8x16B/thread/q, L2-hot); accumulation order bit-identical.
// ---------------------------------------------------------------------------
#define GATE_BLOCKS 512
#define CVT_BLOCKS  1536

__global__ __launch_bounds__(256) void gatecvt_kernel(
    const float* __restrict__ x, const float* __restrict__ wg,
    const float* __restrict__ W,
    int* __restrict__ eid, float* __restrict__ gate,
    u16* __restrict__ xbf, u16* __restrict__ Wbf) {
    const int tid = threadIdx.x;

    if (blockIdx.x >= GATE_BLOCKS) {       // ---- W fp32 -> bf16 ----
        int i = (blockIdx.x - GATE_BLOCKS) * 256 + tid;
        const int n4 = E * H * H / 4;
        const int stride = CVT_BLOCKS * 256;
        for (; i < n4; i += stride) {
            float4 v = ((const float4*)W)[i];
            ushort4 o;
            o.x = f2bf(v.x); o.y = f2bf(v.y); o.z = f2bf(v.z); o.w = f2bf(v.w);
            ((ushort4*)Wbf)[i] = o;
        }
        return;
    }

    // ---- gating, 16 tokens/block (4/wave) ----
    const int wv = tid >> 6, lane = tid & 63;
    const int tbase = blockIdx.x * 16 + wv * 4;
    const int h00 = lane * 4;

    float a[4][8];
    #pragma unroll
    for (int j = 0; j < 4; ++j)
        #pragma unroll
        for (int e = 0; e < 8; ++e) a[j][e] = 0.f;

    #pragma unroll
    for (int q = 0; q < 4; ++q) {
        const int h0 = q * 256 + h00;
        float4 xv[4];
        #pragma unroll
        for (int j = 0; j < 4; ++j)
            xv[j] = *(const float4*)(x + (size_t)(tbase + j) * H + h0);
        #pragma unroll
        for (int j = 0; j < 4; ++j) {
            ushort4 o;
            o.x = f2bf(xv[j].x); o.y = f2bf(xv[j].y);
            o.z = f2bf(xv[j].z); o.w = f2bf(xv[j].w);
            *(ushort4*)(xbf + (size_t)(tbase + j) * H + h0) = o;
        }
        // wg rows h0..h0+3, all 8 experts -> wr[r][e] (register transpose)
        float wr[4][8];
        #pragma unroll
        for (int r = 0; r < 4; ++r) {
            const float4* p = (const float4*)(wg + (size_t)(h0 + r) * E);
            float4 lo = p[0], hi = p[1];
            wr[r][0] = lo.x; wr[r][1] = lo.y; wr[r][2] = lo.z; wr[r][3] = lo.w;
            wr[r][4] = hi.x; wr[r][5] = hi.y; wr[r][6] = hi.z; wr[r][7] = hi.w;
        }
        #pragma unroll
        for (int e = 0; e < 8; ++e)
            #pragma unroll
            for (int j = 0; j < 4; ++j)
                a[j][e] += xv[j].x * wr[0][e] + xv[j].y * wr[1][e]
                         + xv[j].z * wr[2][e] + xv[j].w * wr[3][e];
    }

    const bool b0 = lane & 1, b1 = lane & 2, b2 = lane & 4;
    const int elane = ((lane & 1) << 2) | (lane & 2) | ((lane >> 2) & 1);

    #pragma unroll
    for (int j = 0; j < 4; ++j) {
        float* A = a[j];
        #pragma unroll
        for (int k = 0; k < 4; ++k) {
            float t = b0 ? A[k] : A[k + 4];
            t = __shfl_xor(t, 1);
            A[k] = (b0 ? A[k + 4] : A[k]) + t;
        }
        #pragma unroll
        for (int k = 0; k < 2; ++k) {
            float t = b1 ? A[k] : A[k + 2];
            t = __shfl_xor(t, 2);
            A[k] = (b1 ? A[k + 2] : A[k]) + t;
        }
        {
            float t = b2 ? A[0] : A[1];
            t = __shfl_xor(t, 4);
            A[0] = (b2 ? A[1] : A[0]) + t;
        }
        float v = A[0];
        v += __shfl_xor(v, 8); v += __shfl_xor(v, 16); v += __shfl_xor(v, 32);
        float m = v; int mi = elane;
        #pragma unroll
        for (int off = 1; off <= 4; off <<= 1) {
            float om = __shfl_xor(m, off);
            int   oi = __shfl_xor(mi, off);
            if (om > m || (om == m && oi < mi)) { m = om; mi = oi; }
        }
        float s = expf(v - m);
        s += __shfl_xor(s, 1); s += __shfl_xor(s, 2); s += __shfl_xor(s, 4);
        if (lane == 0) {
            eid[tbase + j]  = mi;
            gate[tbase + j] = 1.0f / s;
        }
    }
}

// ---------------------------------------------------------------------------
// Kernel 2: capacity scan (single block, 256 threads) -- champion version.
// ---------------------------------------------------------------------------
#define TPT 32
__global__ __launch_bounds__(256) void scan_kernel(
    const int* __restrict__ eid, float* __restrict__ gate,
    int* __restrict__ perm) {
    __shared__ int cnt[256][E];
    __shared__ int base[256][E];
    __shared__ int part[E][8];
    const int tid = threadIdx.x;

    for (int i = tid; i < E * CAP; i += 256) perm[i] = -1;

    const int t0 = tid * TPT;
    int c[E];
    #pragma unroll
    for (int e = 0; e < E; ++e) c[e] = 0;
    for (int i = 0; i < TPT; ++i) {
        const int ei = eid[t0 + i];
        #pragma unroll
        for (int e = 0; e < E; ++e) c[e] += (ei == e);
    }
    #pragma unroll
    for (int e = 0; e < E; ++e) cnt[tid][e] = c[e];
    __syncthreads();
    if (tid < 64) {
        const int e = tid >> 3, j = tid & 7;
        int s = 0;
        for (int i = j * 32; i < j * 32 + 32; ++i) s += cnt[i][e];
        part[e][j] = s;
    }
    __syncthreads();
    if (tid < E) {
        int run = 0;
        #pragma unroll
        for (int j = 0; j < 8; ++j) { int v = part[tid][j]; part[tid][j] = run; run += v; }
    }
    __syncthreads();
    if (tid < 64) {
        const int e = tid >> 3, j = tid & 7;
        int run = part[e][j];
        for (int i = j * 32; i < j * 32 + 32; ++i) { base[i][e] = run; run += cnt[i][e]; }
    }
    __syncthreads();
    #pragma unroll
    for (int e = 0; e < E; ++e) c[e] = base[tid][e];
    for (int i = 0; i < TPT; ++i) {
        const int t = t0 + i;
        const int ei = eid[t];
        int pos = 0;
        #pragma unroll
        for (int e = 0; e < E; ++e) if (ei == e) pos = c[e]++;
        if (pos < CAP) perm[ei * CAP + pos] = t;
        else gate[t] = 0.f;               // dropped; kept tokens have gate >= 1/8
    }
}

// ---------------------------------------------------------------------------
// Kernel 3: bf16 gathered GEMM -- champion version, byte-for-byte.
// 512 threads (8 waves as 2x4: 64x32/wave). Tile 128x128, BK=128 (two
// 128x64 halves). XOR-swizzled LDS, global_load_lds width-16. 1-D grid,
// XCD swizzle: e = idx&7. idx >= 512: zero-dropped-rows plane.
// ---------------------------------------------------------------------------
__global__ __launch_bounds__(512, 4) void moe_gemm_bf(
    const u16* __restrict__ xbf, const u16* __restrict__ Wbf,
    const float* __restrict__ bias, const int* __restrict__ perm,
    const float* __restrict__ gate, float* __restrict__ out) {
    __shared__ __align__(16) u16 As[2][128 * 64];   // 32 KB
    __shared__ __align__(16) u16 Bs[2][128 * 64];   // 32 KB
    __shared__ int   perm_s[128];
    __shared__ float gate_s[128];

    const int tid = threadIdx.x;
    const int idx = blockIdx.x;

    if (idx >= 512) {               // ---- zero rows of dropped tokens ----
        const int t = (idx - 512) * 128 + (tid >> 2);
        if (gate[t] == 0.f) {
            const int part = tid & 3;
            float4 z = make_float4(0.f, 0.f, 0.f, 0.f);
            float4* o = (float4*)(out + (size_t)t * H + part * 256);
            #pragma unroll
            for (int i = 0; i < 64; ++i) o[i] = z;
        }
        return;
    }

    const int fb = idx >> 6;          // feature block
    const int mb = (idx >> 3) & 7;    // slot block
    const int e  = idx & 7;           // expert -> XCD (round-robin heuristic)

    if (tid < 128) {
        const int t = perm[e * CAP + mb * 128 + tid];
        perm_s[tid] = t;
        gate_s[tid] = (t >= 0) ? gate[t] : 0.f;
    }
    __syncthreads();

    const int lane = tid & 63;
    const int wv = tid >> 6;          // 0..7
    const int wm = wv >> 2;           // 0..1 : 64-row half
    const int wn = wv & 3;            // 0..3 : 32-col quarter
    const int l16 = lane & 15, quad = lane >> 4;

    // staging: per half-buffer, wave wv covers rows [wv*16, wv*16+16)
    // (2 instrs of 8 rows); chunk slot = lane&7, global chunk = slot ^ (row&7)
    const int rl  = lane >> 3;        // row within 8-row group
    const int cch = lane & 7;
    const int gch = cch ^ rl;
    const u16* ga[2]; const u16* gb[2];
    #pragma unroll
    for (int q = 0; q < 2; ++q) {
        const int r = wv * 16 + q * 8 + rl;
        const int tA = perm_s[r];
        const int tok = tA >= 0 ? tA : 0;
        ga[q] = xbf + (size_t)tok * H + gch * 8;
        gb[q] = Wbf + (size_t)e * H * H + (size_t)(fb * 128 + r) * H + gch * 8;
    }

    f32x4 acc[4][2] = {};

    for (int kt = 0; kt < H / 128; ++kt) {
        __syncthreads();
        #pragma unroll
        for (int hb = 0; hb < 2; ++hb)
            #pragma unroll
            for (int q = 0; q < 2; ++q) {
                u16* la = &As[hb][(wv * 16 + q * 8) * 64 + lane * 8];
                u16* lb = &Bs[hb][(wv * 16 + q * 8) * 64 + lane * 8];
                gld16(ga[q] + hb * 64, la);
                gld16(gb[q] + hb * 64, lb);
            }
        #pragma unroll
        for (int q = 0; q < 2; ++q) { ga[q] += 128; gb[q] += 128; }
        __syncthreads();
        #pragma unroll
        for (int hb = 0; hb < 2; ++hb)
            #pragma unroll
            for (int s = 0; s < 2; ++s) {
                bf16x8 af[4], bfr[2];
                const int cc = (s * 4 + quad) ^ (l16 & 7);
                #pragma unroll
                for (int i = 0; i < 4; ++i)
                    af[i] = *(const bf16x8*)&As[hb][(wm * 64 + i * 16 + l16) * 64 + cc * 8];
                #pragma unroll
                for (int i = 0; i < 2; ++i)
                    bfr[i] = *(const bf16x8*)&Bs[hb][(wn * 32 + i * 16 + l16) * 64 + cc * 8];
                #pragma unroll
                for (int mi = 0; mi < 4; ++mi)
                    #pragma unroll
                    for (int ni = 0; ni < 2; ++ni)
                        acc[mi][ni] = __builtin_amdgcn_mfma_f32_16x16x32_bf16(
                            af[mi], bfr[ni], acc[mi][ni], 0, 0, 0);
            }
    }

    // epilogue: C/D layout col=lane&15, row=quad*4+reg
    float bv[2];
    #pragma unroll
    for (int ni = 0; ni < 2; ++ni)
        bv[ni] = bias[e * H + fb * 128 + wn * 32 + ni * 16 + l16];

    #pragma unroll
    for (int mi = 0; mi < 4; ++mi) {
        #pragma unroll
        for (int r = 0; r < 4; ++r) {
            const int rowl = wm * 64 + mi * 16 + quad * 4 + r;
            const int t = perm_s[rowl];
            if (t < 0) continue;
            const float g = gate_s[rowl];
            float* orow = out + (size_t)t * H + fb * 128 + wn * 32;
            #pragma unroll
            for (int ni = 0; ni < 2; ++ni)
                orow[ni * 16 + l16] = g * (acc[mi][ni][r] + bv[ni]);
        }
    }
}

extern "C" void kernel_launch(void* const* d_in, const int* in_sizes, int n_in,
                              void* d_out, int out_size, void* d_ws, size_t ws_size,
                              hipStream_t stream) {
    const float* x    = (const float*)d_in[0];  // [T,H]
    const float* wg   = (const float*)d_in[1];  // [H,E]
    const float* W    = (const float*)d_in[2];  // [E,H,H]
    const float* bias = (const float*)d_in[3];  // [E,H]
    float* out = (float*)d_out;

    // ws: eid[T] | gate[T] | perm[E*CAP] | xbf[T*H] bf16 | Wbf[E*H*H] bf16
    int*   eid  = (int*)d_ws;
    float* gate = (float*)((char*)d_ws + (size_t)T * 4);
    int*   perm = (int*)((char*)d_ws + (size_t)T * 8);
    u16*   xbf  = (u16*)((char*)d_ws + (size_t)T * 12);
    u16*   Wbf  = xbf + (size_t)T * H;

    gatecvt_kernel<<<GATE_BLOCKS + CVT_BLOCKS, 256, 0, stream>>>(
        x, wg, W, eid, gate, xbf, Wbf);
    scan_kernel<<<1, 256, 0, stream>>>(eid, gate, perm);
    moe_gemm_bf<<<512 + 64, 512, 0, stream>>>(xbf, Wbf, bias, perm, gate, out);
}